// Round 6
// baseline (126.245 us; speedup 1.0000x reference)
//
#include <hip/hip_runtime.h>
#include <hip/hip_bf16.h>
#include <stdint.h>

// ---------------------------------------------------------------------------
// Decoder_10110353014984: LIF multistep (T=4) + linear head
//   x: [4,64,196,512] f32, W: [1000,512] f32, b: [1000] f32
//   y: [4,64,196,1000] f32
// R6 = R5 with the GEMM main loop DE-BARRIERED: R2's per-phase
//      s_barrier/lgkmcnt(0)/sched_barrier/setprio lockstepped all 8 waves
//      (everyone reads LDS together -> 8-way port contention, then everyone
//      MFMAs together -> port idle). Counter evidence: each pipe's util ~=
//      its total work / wall => pipes sequential. Now: per K-tile just
//      {8 prefetch gload_lds; 2x(12 ds_read_b128 + 64 MFMA); __syncthreads}
//      and let waves self-stagger (compiler emits fine-grained lgkmcnt).
// ---------------------------------------------------------------------------

typedef __attribute__((ext_vector_type(8))) short bf16x8;
typedef __attribute__((ext_vector_type(4))) float f32x4;

#define AS1(p) ((const __attribute__((address_space(1))) void*)(p))
#define AS3(p) ((__attribute__((address_space(3))) void*)(p))

static constexpr int     T_STEPS = 4;
static constexpr int64_t ESP     = 6422528;   // B*N*D = 64*196*512
static constexpr int     K_DIM   = 512;
static constexpr int     C_DIM   = 1000;
static constexpr int64_t M_ROWS  = 50176;     // T*B*N

__device__ __forceinline__ unsigned short f2bf(float f) {
  unsigned int u = __float_as_uint(f);
  u += 0x7FFFu + ((u >> 16) & 1u);            // round-to-nearest-even
  return (unsigned short)(u >> 16);
}

// ---------------------------------------------------------------------------
// Kernel 1: LIF dynamics -> bf16 spikes. Bit-exact vs reference:
// v += (x - v) * 0.5f (exact *0.5), spike iff v >= 1.0f, hard reset.
// ---------------------------------------------------------------------------
__global__ void lif_kernel(const float* __restrict__ x,
                           unsigned short* __restrict__ S) {
  const int64_t stride = (int64_t)gridDim.x * blockDim.x;
  const int64_t nquads = ESP / 4;
  for (int64_t q = (int64_t)blockIdx.x * blockDim.x + threadIdx.x;
       q < nquads; q += stride) {
    const int64_t s0 = q << 2;
    float v[4] = {0.f, 0.f, 0.f, 0.f};
#pragma unroll
    for (int t = 0; t < T_STEPS; ++t) {
      const float4 xt = *(const float4*)(x + (int64_t)t * ESP + s0);
      const float xa[4] = {xt.x, xt.y, xt.z, xt.w};
      ushort4 sp;
      unsigned short* spp = &sp.x;
#pragma unroll
      for (int j = 0; j < 4; ++j) {
        v[j] = v[j] + (xa[j] - v[j]) * 0.5f;   // charge
        const bool fire = (v[j] >= 1.0f);
        spp[j] = fire ? (unsigned short)0x3F80 : (unsigned short)0; // bf16 1/0
        if (fire) v[j] = 0.0f;                 // hard reset
      }
      *(ushort4*)(S + (int64_t)t * ESP + s0) = sp;
    }
  }
}

// ---------------------------------------------------------------------------
// Kernel 2: W f32[1000,512] -> bf16[1024,512], rows 1000..1023 zeroed.
// ---------------------------------------------------------------------------
__global__ void wconv_kernel(const float* __restrict__ W,
                             unsigned short* __restrict__ Wb) {
  const int idx = blockIdx.x * blockDim.x + threadIdx.x;  // 0..131071
  const int64_t base = (int64_t)idx * 4;
  const int row = (int)(base >> 9);
  ushort4 o;
  if (row < C_DIM) {
    const float4 wv = *(const float4*)(W + base);
    o.x = f2bf(wv.x); o.y = f2bf(wv.y); o.z = f2bf(wv.z); o.w = f2bf(wv.w);
  } else {
    o.x = o.y = o.z = o.w = 0;
  }
  *(ushort4*)(Wb + base) = o;
}

// ---------------------------------------------------------------------------
// Kernel 3: GEMM  Y[m,c] = sum_d S[m,d] * Wb[c,d] + b[c]
// 256x256 tile, BK=64, 512 threads (8 waves, 2Mx4N -> wave 128x64), dbuf
// 128KB LDS. Per K-tile: prefetch 8 gload_lds for t+1, then 2 half-tiles of
// {12 ds_read_b128 + 64 MFMA} with NO intra-tile barriers; one __syncthreads
// per tile (drains vmcnt -> buffer swap safe). Epilogue: LDS-staged
// full-line nontemporal streaming (R5, proven).
// ---------------------------------------------------------------------------
__global__ __launch_bounds__(512) void gemm_kernel(
    const unsigned short* __restrict__ S,
    const unsigned short* __restrict__ Wb,
    const float* __restrict__ bias,
    float* __restrict__ Y) {
  __shared__ __attribute__((aligned(16))) unsigned short As[2][256 * 64];
  __shared__ __attribute__((aligned(16))) unsigned short Bs[2][256 * 64];

  const int tid  = threadIdx.x;
  const int lane = tid & 63;
  const int wid  = tid >> 6;      // 0..7
  const int wm   = wid >> 2;      // 0..1  (M half: 128 rows)
  const int wn   = wid & 3;       // 0..3  (N quarter: 64 cols)

  // XCD-aware swizzle: 784 blocks, bijective; the 4 N-tiles of an M-tile are
  // adjacent on one XCD (S tile L2-shared; FETCH 42MB measured in R2).
  const int bid   = blockIdx.x;
  const int swz   = (bid & 7) * 98 + (bid >> 3);
  const int mtile = swz >> 2;
  const int ntile = swz & 3;
  const int64_t row0 = (int64_t)mtile * 256;
  const int     c0   = ntile * 256;

  // staging: LDS dest is wave-uniform base (+ lane*16 by HW); swizzle on the
  // GLOBAL source column: ((lane&7) ^ (lane>>3)) << 4.
  const int srow = lane >> 3;                 // 0..7
  const int skb  = ((lane & 7) ^ srow) << 4;

  const char* Sg = (const char*)S;
  const char* Wg = (const char*)Wb;

  f32x4 acc[8][4] = {};

  auto stageA = [&](int buf, int k0, int i) {
    const int64_t gr = row0 + i * 64 + wid * 8 + srow;
    __builtin_amdgcn_global_load_lds(
        AS1(Sg + (gr * K_DIM + k0) * 2 + skb),
        AS3((char*)&As[buf][0] + (i * 64 + wid * 8) * 128), 16, 0, 0);
  };
  auto stageB = [&](int buf, int k0, int i) {
    const int64_t gr = (int64_t)c0 + i * 64 + wid * 8 + srow;
    __builtin_amdgcn_global_load_lds(
        AS1(Wg + (gr * K_DIM + k0) * 2 + skb),
        AS3((char*)&Bs[buf][0] + (i * 64 + wid * 8) * 128), 16, 0, 0);
  };

  // prologue: stage K-tile 0 into buf 0
#pragma unroll
  for (int i = 0; i < 4; ++i) stageA(0, 0, i);
#pragma unroll
  for (int i = 0; i < 4; ++i) stageB(0, 0, i);
  __syncthreads();

  const int lr = lane & 15;
  const int lk = (lane >> 4) * 16;

  int cur = 0;
  for (int t = 0; t < 8; ++t) {            // 8 K-tiles of 64
    const int  k0n = (t + 1) * 64;
    const int  nxt = cur ^ 1;
    const char* Ab = (const char*)&As[cur][0];
    const char* Bb = (const char*)&Bs[cur][0];

    // prefetch next K-tile first: vmem latency hides under this tile's work
    if (t < 7) {
#pragma unroll
      for (int i = 0; i < 4; ++i) stageA(nxt, k0n, i);
#pragma unroll
      for (int i = 0; i < 4; ++i) stageB(nxt, k0n, i);
    }

#pragma unroll
    for (int half = 0; half < 2; ++half) { // kk slice of BK=64
      const int kb = half * 64 + lk;
      bf16x8 afr[8], bfr[4];
#pragma unroll
      for (int mi = 0; mi < 8; ++mi) {
        const int r = wm * 128 + mi * 16 + lr;
        afr[mi] = *(const bf16x8*)(Ab + r * 128 + (kb ^ ((r & 7) << 4)));
      }
#pragma unroll
      for (int nj = 0; nj < 4; ++nj) {
        const int r = wn * 64 + nj * 16 + lr;
        bfr[nj] = *(const bf16x8*)(Bb + r * 128 + (kb ^ ((r & 7) << 4)));
      }
#pragma unroll
      for (int mi = 0; mi < 8; ++mi)
#pragma unroll
        for (int nj = 0; nj < 4; ++nj)
          acc[mi][nj] = __builtin_amdgcn_mfma_f32_16x16x32_bf16(
              afr[mi], bfr[nj], acc[mi][nj], 0, 0, 0);
    }
    __syncthreads();   // drains vmcnt+lgkmcnt: next tile staged, bufs safe
    cur = nxt;
  }

  // ---- epilogue: LDS-staged full-line streaming stores (R5, proven) ----
  // acc[mi][nj][r] belongs to Y[row0 + wm*128 + mi*16 + (lane>>4)*4 + r]
  //                            [c0 + wn*64 + nj*16 + lr]
  float bvn[4];
#pragma unroll
  for (int nj = 0; nj < 4; ++nj) {
    const int c = c0 + wn * 64 + nj * 16 + lr;
    bvn[nj] = (c < C_DIM) ? bias[c] : 0.f;
  }

  char* obuf = (char*)&As[0][0];                 // 64KB (As[0]+As[1]), dead
  const int cw4 = (C_DIM - c0 < 256 ? C_DIM - c0 : 256) * 4; // panel bytes/row
  const int rw  = tid >> 6;                      // row-in-pass (wave id)
  const int cb  = (tid & 63) * 16;               // byte offset within row

#pragma unroll
  for (int slice = 0; slice < 4; ++slice) {
    __syncthreads();                             // LDS free for this slice
    if (wm == (slice >> 1)) {
      const int mi0 = (slice & 1) * 4;
#pragma unroll
      for (int mi2 = 0; mi2 < 4; ++mi2) {
#pragma unroll
        for (int nj = 0; nj < 4; ++nj) {
          const int cl = (wn * 64 + nj * 16 + lr) * 4;
#pragma unroll
          for (int r = 0; r < 4; ++r) {
            const int rl = mi2 * 16 + (lane >> 4) * 4 + r;   // 0..63
            *(float*)(obuf + ((rl * 1024 + cl) ^ ((rl & 7) << 4))) =
                acc[mi0 + mi2][nj][r] + bvn[nj];
          }
        }
      }
    }
    __syncthreads();                             // slice fully written
    // stream: 8 passes x 8 rows; one wave owns one row (1024B contiguous)
#pragma unroll
    for (int pass = 0; pass < 8; ++pass) {
      const int rl = pass * 8 + rw;
      const f32x4 v =
          *(const f32x4*)(obuf + ((rl * 1024 + cb) ^ ((rl & 7) << 4)));
      if (cb < cw4) {
        const int64_t m = row0 + slice * 64 + rl;
        f32x4* dst = (f32x4*)((char*)(Y + m * (int64_t)C_DIM + c0) + cb);
        __builtin_nontemporal_store(v, dst);
      }
    }
  }
}

// ---------------------------------------------------------------------------
extern "C" void kernel_launch(void* const* d_in, const int* in_sizes, int n_in,
                              void* d_out, int out_size, void* d_ws, size_t ws_size,
                              hipStream_t stream) {
  const float* x = (const float*)d_in[0];
  const float* W = (const float*)d_in[1];
  const float* b = (const float*)d_in[2];
  float* Y = (float*)d_out;

  unsigned short* S  = (unsigned short*)d_ws;            // 50176*512 bf16 = 51.4 MB
  unsigned short* Wb = S + (size_t)M_ROWS * K_DIM;       // 1024*512 bf16  =  1.0 MB

  hipLaunchKernelGGL(wconv_kernel, dim3(512), dim3(256), 0, stream, W, Wb);
  hipLaunchKernelGGL(lif_kernel, dim3(2048), dim3(256), 0, stream, x, S);
  hipLaunchKernelGGL(gemm_kernel, dim3(784), dim3(512), 0, stream, S, Wb, b, Y);
}

// Round 7
// 99.063 us; speedup vs baseline: 1.2744x; 1.2744x over previous
//
#include <hip/hip_runtime.h>
#include <hip/hip_bf16.h>
#include <stdint.h>

// ---------------------------------------------------------------------------
// Decoder_10110353014984: LIF multistep (T=4) + linear head
//   x: [4,64,196,512] f32, W: [1000,512] f32, b: [1000] f32
//   y: [4,64,196,1000] f32
// R7: GEMM back to the m97-proven 128x128 geometry so 3 blocks/CU co-reside
//     (32KB single-buffered LDS, 256 thr, __launch_bounds__(256,3)).
//     Fixes R2-R6's structural limits: 1 block/CU tail quantization (25%
//     wasted round) and no cross-block phase overlap. Keeps: source-swizzled
//     global_load_lds staging, XCD c-panel grouping, LDS-staged full-line
//     nontemporal streaming epilogue (R5).
// ---------------------------------------------------------------------------

typedef __attribute__((ext_vector_type(8))) short bf16x8;
typedef __attribute__((ext_vector_type(4))) float f32x4;

#define AS1(p) ((const __attribute__((address_space(1))) void*)(p))
#define AS3(p) ((__attribute__((address_space(3))) void*)(p))

static constexpr int     T_STEPS = 4;
static constexpr int64_t ESP     = 6422528;   // B*N*D = 64*196*512
static constexpr int     K_DIM   = 512;
static constexpr int     C_DIM   = 1000;
static constexpr int64_t M_ROWS  = 50176;     // T*B*N

__device__ __forceinline__ unsigned short f2bf(float f) {
  unsigned int u = __float_as_uint(f);
  u += 0x7FFFu + ((u >> 16) & 1u);            // round-to-nearest-even
  return (unsigned short)(u >> 16);
}

// ---------------------------------------------------------------------------
// Kernel 1: LIF dynamics -> bf16 spikes. Bit-exact vs reference:
// v += (x - v) * 0.5f (exact *0.5), spike iff v >= 1.0f, hard reset.
// ---------------------------------------------------------------------------
__global__ void lif_kernel(const float* __restrict__ x,
                           unsigned short* __restrict__ S) {
  const int64_t stride = (int64_t)gridDim.x * blockDim.x;
  const int64_t nquads = ESP / 4;
  for (int64_t q = (int64_t)blockIdx.x * blockDim.x + threadIdx.x;
       q < nquads; q += stride) {
    const int64_t s0 = q << 2;
    float v[4] = {0.f, 0.f, 0.f, 0.f};
#pragma unroll
    for (int t = 0; t < T_STEPS; ++t) {
      const float4 xt = *(const float4*)(x + (int64_t)t * ESP + s0);
      const float xa[4] = {xt.x, xt.y, xt.z, xt.w};
      ushort4 sp;
      unsigned short* spp = &sp.x;
#pragma unroll
      for (int j = 0; j < 4; ++j) {
        v[j] = v[j] + (xa[j] - v[j]) * 0.5f;   // charge
        const bool fire = (v[j] >= 1.0f);
        spp[j] = fire ? (unsigned short)0x3F80 : (unsigned short)0; // bf16 1/0
        if (fire) v[j] = 0.0f;                 // hard reset
      }
      *(ushort4*)(S + (int64_t)t * ESP + s0) = sp;
    }
  }
}

// ---------------------------------------------------------------------------
// Kernel 2: W f32[1000,512] -> bf16[1024,512], rows 1000..1023 zeroed.
// ---------------------------------------------------------------------------
__global__ void wconv_kernel(const float* __restrict__ W,
                             unsigned short* __restrict__ Wb) {
  const int idx = blockIdx.x * blockDim.x + threadIdx.x;  // 0..131071
  const int64_t base = (int64_t)idx * 4;
  const int row = (int)(base >> 9);
  ushort4 o;
  if (row < C_DIM) {
    const float4 wv = *(const float4*)(W + base);
    o.x = f2bf(wv.x); o.y = f2bf(wv.y); o.z = f2bf(wv.z); o.w = f2bf(wv.w);
  } else {
    o.x = o.y = o.z = o.w = 0;
  }
  *(ushort4*)(Wb + base) = o;
}

// ---------------------------------------------------------------------------
// Kernel 3: GEMM  Y[m,c] = sum_d S[m,d] * Wb[c,d] + b[c]
// 128x128 tile, BK=64, 256 threads (4 waves 2Mx2N, wave tile 64x64),
// single-buffered 32KB LDS, 2-barrier K-loop (m97 structure, 3 blocks/CU).
// Grid 3136 = 392 m-tiles x 8 c-panels; XCD grouping: the 8 c-panels of an
// m-tile are consecutive on one XCD (A-tile = 128KB, L2-shared).
// Epilogue: 2 slices of 64 rows staged in LDS, streamed as full 128B lines
// (one wave = 2 rows x 512B per pass), nontemporal.
// ---------------------------------------------------------------------------
__global__ __launch_bounds__(256, 3) void gemm_kernel(
    const unsigned short* __restrict__ S,
    const unsigned short* __restrict__ Wb,
    const float* __restrict__ bias,
    float* __restrict__ Y) {
  __shared__ __attribute__((aligned(16))) unsigned short As[128 * 64];
  __shared__ __attribute__((aligned(16))) unsigned short Bs[128 * 64];

  const int tid  = threadIdx.x;
  const int lane = tid & 63;
  const int wid  = tid >> 6;      // 0..3
  const int wm   = wid >> 1;      // 0..1  (M half: 64 rows)
  const int wn   = wid & 1;       // 0..1  (N half: 64 cols)

  // XCD grouping: bid%8 = XCD (round-robin dispatch). Per XCD: 392 blocks,
  // j>>3 = local m-tile (49 per XCD), j&7 = c-panel -> 8 siblings adjacent.
  const int bid   = blockIdx.x;
  const int xcd   = bid & 7;
  const int j     = bid >> 3;           // 0..391
  const int mtile = xcd * 49 + (j >> 3);
  const int ntile = j & 7;
  const int64_t row0 = (int64_t)mtile * 128;
  const int     c0   = ntile * 128;

  // staging: one issue = 256 thr x 16B = 4KB = 32 rows x 128B. LDS dest is
  // wave-uniform + lane*16 (linear); swizzle on the GLOBAL source column.
  const int srow = lane >> 3;                 // 0..7
  const int skb  = ((lane & 7) ^ srow) << 4;

  const char* Sg = (const char*)S;
  const char* Wg = (const char*)Wb;
  char* Ab = (char*)As;
  char* Bb = (char*)Bs;

  f32x4 acc[4][4] = {};

  const int lr = lane & 15;
  const int lk = (lane >> 4) * 16;

  for (int t = 0; t < 8; ++t) {            // 8 K-tiles of 64
    const int k0 = t * 64;
#pragma unroll
    for (int i = 0; i < 4; ++i) {          // A: 128 rows = 4 issues
      const int rr = i * 32 + wid * 8;     // uniform row base
      __builtin_amdgcn_global_load_lds(
          AS1(Sg + ((row0 + rr + srow) * (int64_t)K_DIM + k0) * 2 + skb),
          AS3(Ab + rr * 128), 16, 0, 0);
    }
#pragma unroll
    for (int i = 0; i < 4; ++i) {          // B: 128 rows = 4 issues
      const int rr = i * 32 + wid * 8;
      __builtin_amdgcn_global_load_lds(
          AS1(Wg + (((int64_t)c0 + rr + srow) * K_DIM + k0) * 2 + skb),
          AS3(Bb + rr * 128), 16, 0, 0);
    }
    __syncthreads();                       // staging complete

#pragma unroll
    for (int half = 0; half < 2; ++half) { // kk slice of BK=64
      const int kb = half * 64 + lk;
      bf16x8 afr[4], bfr[4];
#pragma unroll
      for (int mi = 0; mi < 4; ++mi) {
        const int r = wm * 64 + mi * 16 + lr;
        afr[mi] = *(const bf16x8*)(Ab + r * 128 + (kb ^ ((r & 7) << 4)));
      }
#pragma unroll
      for (int nj = 0; nj < 4; ++nj) {
        const int r = wn * 64 + nj * 16 + lr;
        bfr[nj] = *(const bf16x8*)(Bb + r * 128 + (kb ^ ((r & 7) << 4)));
      }
#pragma unroll
      for (int mi = 0; mi < 4; ++mi)
#pragma unroll
        for (int nj = 0; nj < 4; ++nj)
          acc[mi][nj] = __builtin_amdgcn_mfma_f32_16x16x32_bf16(
              afr[mi], bfr[nj], acc[mi][nj], 0, 0, 0);
    }
    __syncthreads();                       // reads done; LDS reusable
  }

  // ---- epilogue: LDS-staged full-line streaming stores ----
  // acc[mi][nj][r] -> Y[row0 + wm*64 + mi*16 + (lane>>4)*4 + r]
  //                    [c0 + wn*64 + nj*16 + lr]
  float bvn[4];
#pragma unroll
  for (int nj = 0; nj < 4; ++nj) {
    const int c = c0 + wn * 64 + nj * 16 + lr;
    bvn[nj] = (c < C_DIM) ? bias[c] : 0.f;
  }

  char* obuf = (char*)&As[0];                    // 32KB (As+Bs), dead now
  const int cwb = (C_DIM - c0 < 128 ? C_DIM - c0 : 128) * 4; // bytes/row
  const int rwp = wid * 2;                       // wave's row pair base
  const int rsel = lane >> 5;                    // 0/1 within pair
  const int cb  = (lane & 31) * 16;              // byte col within row

#pragma unroll
  for (int slice = 0; slice < 2; ++slice) {      // 64 rows each
    __syncthreads();                             // LDS free for this slice
    if (wm == slice) {
#pragma unroll
      for (int mi = 0; mi < 4; ++mi) {
#pragma unroll
        for (int nj = 0; nj < 4; ++nj) {
          const int cl = (wn * 64 + nj * 16 + lr) * 4;
#pragma unroll
          for (int r = 0; r < 4; ++r) {
            const int rl = mi * 16 + (lane >> 4) * 4 + r;    // 0..63
            *(float*)(obuf + ((rl * 512 + cl) ^ ((rl & 7) << 4))) =
                acc[mi][nj][r] + bvn[nj];
          }
        }
      }
    }
    __syncthreads();                             // slice fully written
    // stream: 8 passes; one wave covers 2 rows x 512B (full 128B lines)
#pragma unroll
    for (int pass = 0; pass < 8; ++pass) {
      const int rl = pass * 8 + rwp + rsel;      // 0..63
      const f32x4 v =
          *(const f32x4*)(obuf + ((rl * 512 + cb) ^ ((rl & 7) << 4)));
      if (cb < cwb) {
        const int64_t m = row0 + slice * 64 + rl;
        f32x4* dst = (f32x4*)((char*)(Y + m * (int64_t)C_DIM) + c0 * 4 + cb);
        __builtin_nontemporal_store(v, dst);
      }
    }
  }
}

// ---------------------------------------------------------------------------
extern "C" void kernel_launch(void* const* d_in, const int* in_sizes, int n_in,
                              void* d_out, int out_size, void* d_ws, size_t ws_size,
                              hipStream_t stream) {
  const float* x = (const float*)d_in[0];
  const float* W = (const float*)d_in[1];
  const float* b = (const float*)d_in[2];
  float* Y = (float*)d_out;

  unsigned short* S  = (unsigned short*)d_ws;            // 50176*512 bf16 = 51.4 MB
  unsigned short* Wb = S + (size_t)M_ROWS * K_DIM;       // 1024*512 bf16  =  1.0 MB

  hipLaunchKernelGGL(wconv_kernel, dim3(512), dim3(256), 0, stream, W, Wb);
  hipLaunchKernelGGL(lif_kernel, dim3(2048), dim3(256), 0, stream, x, S);
  hipLaunchKernelGGL(gemm_kernel, dim3(3136), dim3(256), 0, stream, S, Wb, b, Y);
}

// Round 8
// 94.271 us; speedup vs baseline: 1.3392x; 1.0508x over previous
//
#include <hip/hip_runtime.h>
#include <hip/hip_bf16.h>
#include <stdint.h>

// ---------------------------------------------------------------------------
// Decoder_10110353014984: LIF multistep (T=4) + linear head
//   x: [4,64,196,512] f32, W: [1000,512] f32, b: [1000] f32
//   y: [4,64,196,1000] f32
// R8 = R7 with: (a) gemm __launch_bounds__(256,4) -> 4 blocks/CU (128KB LDS,
//      16 waves/CU; tail 4.08 -> 3.06 rounds), (b) wconv folded into the LIF
//      kernel as extra blocks (one launch gap removed), (c) LIF grid 3136 ->
//      exactly 2 float4-quads per thread.
// ---------------------------------------------------------------------------

typedef __attribute__((ext_vector_type(8))) short bf16x8;
typedef __attribute__((ext_vector_type(4))) float f32x4;

#define AS1(p) ((const __attribute__((address_space(1))) void*)(p))
#define AS3(p) ((__attribute__((address_space(3))) void*)(p))

static constexpr int     T_STEPS = 4;
static constexpr int64_t ESP     = 6422528;   // B*N*D = 64*196*512
static constexpr int     K_DIM   = 512;
static constexpr int     C_DIM   = 1000;
static constexpr int64_t M_ROWS  = 50176;     // T*B*N

static constexpr int LIF_BLOCKS = 3136;       // 3136*256 thr * 2 quads = ESP/4
static constexpr int WCV_BLOCKS = 512;        // 512*256*4 elem = 1024*512

__device__ __forceinline__ unsigned short f2bf(float f) {
  unsigned int u = __float_as_uint(f);
  u += 0x7FFFu + ((u >> 16) & 1u);            // round-to-nearest-even
  return (unsigned short)(u >> 16);
}

// ---------------------------------------------------------------------------
// Kernel 1: LIF dynamics -> bf16 spikes, plus W f32->bf16 conversion in the
// trailing 512 blocks (uniform per-block branch). LIF is bit-exact vs ref:
// v += (x - v) * 0.5f (exact *0.5), spike iff v >= 1.0f, hard reset.
// ---------------------------------------------------------------------------
__global__ void lifw_kernel(const float* __restrict__ x,
                            unsigned short* __restrict__ S,
                            const float* __restrict__ W,
                            unsigned short* __restrict__ Wb) {
  const int b = blockIdx.x;
  if (b >= LIF_BLOCKS) {
    // ---- W conversion: rows 1000..1023 zeroed ----
    const int idx = (b - LIF_BLOCKS) * 256 + threadIdx.x;  // 0..131071
    const int64_t base = (int64_t)idx * 4;
    const int row = (int)(base >> 9);
    ushort4 o;
    if (row < C_DIM) {
      const float4 wv = *(const float4*)(W + base);
      o.x = f2bf(wv.x); o.y = f2bf(wv.y); o.z = f2bf(wv.z); o.w = f2bf(wv.w);
    } else {
      o.x = o.y = o.z = o.w = 0;
    }
    *(ushort4*)(Wb + base) = o;
    return;
  }
  // ---- LIF: exactly 2 quads per thread ----
  const int64_t tb = (int64_t)b * 256 + threadIdx.x;
#pragma unroll
  for (int it = 0; it < 2; ++it) {
    const int64_t s0 = (tb + (int64_t)it * LIF_BLOCKS * 256) << 2;
    float v[4] = {0.f, 0.f, 0.f, 0.f};
#pragma unroll
    for (int t = 0; t < T_STEPS; ++t) {
      const float4 xt = *(const float4*)(x + (int64_t)t * ESP + s0);
      const float xa[4] = {xt.x, xt.y, xt.z, xt.w};
      ushort4 sp;
      unsigned short* spp = &sp.x;
#pragma unroll
      for (int j = 0; j < 4; ++j) {
        v[j] = v[j] + (xa[j] - v[j]) * 0.5f;   // charge
        const bool fire = (v[j] >= 1.0f);
        spp[j] = fire ? (unsigned short)0x3F80 : (unsigned short)0; // bf16 1/0
        if (fire) v[j] = 0.0f;                 // hard reset
      }
      *(ushort4*)(S + (int64_t)t * ESP + s0) = sp;
    }
  }
}

// ---------------------------------------------------------------------------
// Kernel 2: GEMM  Y[m,c] = sum_d S[m,d] * Wb[c,d] + b[c]
// 128x128 tile, BK=64, 256 threads (4 waves 2Mx2N, wave tile 64x64),
// single-buffered 32KB LDS, 2-barrier K-loop (m97 structure, 4 blocks/CU).
// Grid 3136 = 392 m-tiles x 8 c-panels; XCD grouping: the 8 c-panels of an
// m-tile are consecutive on one XCD (A-tile = 128KB, L2-shared).
// Epilogue: 2 slices of 64 rows staged in LDS, streamed as full 128B lines
// (one wave = 2 rows x 512B per pass), nontemporal.
// ---------------------------------------------------------------------------
__global__ __launch_bounds__(256, 4) void gemm_kernel(
    const unsigned short* __restrict__ S,
    const unsigned short* __restrict__ Wb,
    const float* __restrict__ bias,
    float* __restrict__ Y) {
  __shared__ __attribute__((aligned(16))) unsigned short As[128 * 64];
  __shared__ __attribute__((aligned(16))) unsigned short Bs[128 * 64];

  const int tid  = threadIdx.x;
  const int lane = tid & 63;
  const int wid  = tid >> 6;      // 0..3
  const int wm   = wid >> 1;      // 0..1  (M half: 64 rows)
  const int wn   = wid & 1;       // 0..1  (N half: 64 cols)

  // XCD grouping: bid%8 = XCD (round-robin dispatch). Per XCD: 392 blocks,
  // j>>3 = local m-tile (49 per XCD), j&7 = c-panel -> 8 siblings adjacent.
  const int bid   = blockIdx.x;
  const int xcd   = bid & 7;
  const int j     = bid >> 3;           // 0..391
  const int mtile = xcd * 49 + (j >> 3);
  const int ntile = j & 7;
  const int64_t row0 = (int64_t)mtile * 128;
  const int     c0   = ntile * 128;

  // staging: one issue = 256 thr x 16B = 4KB = 32 rows x 128B. LDS dest is
  // wave-uniform + lane*16 (linear); swizzle on the GLOBAL source column.
  const int srow = lane >> 3;                 // 0..7
  const int skb  = ((lane & 7) ^ srow) << 4;

  const char* Sg = (const char*)S;
  const char* Wg = (const char*)Wb;
  char* Ab = (char*)As;
  char* Bb = (char*)Bs;

  f32x4 acc[4][4] = {};

  const int lr = lane & 15;
  const int lk = (lane >> 4) * 16;

  for (int t = 0; t < 8; ++t) {            // 8 K-tiles of 64
    const int k0 = t * 64;
#pragma unroll
    for (int i = 0; i < 4; ++i) {          // A: 128 rows = 4 issues
      const int rr = i * 32 + wid * 8;     // uniform row base
      __builtin_amdgcn_global_load_lds(
          AS1(Sg + ((row0 + rr + srow) * (int64_t)K_DIM + k0) * 2 + skb),
          AS3(Ab + rr * 128), 16, 0, 0);
    }
#pragma unroll
    for (int i = 0; i < 4; ++i) {          // B: 128 rows = 4 issues
      const int rr = i * 32 + wid * 8;
      __builtin_amdgcn_global_load_lds(
          AS1(Wg + (((int64_t)c0 + rr + srow) * K_DIM + k0) * 2 + skb),
          AS3(Bb + rr * 128), 16, 0, 0);
    }
    __syncthreads();                       // staging complete

#pragma unroll
    for (int half = 0; half < 2; ++half) { // kk slice of BK=64
      const int kb = half * 64 + lk;
      bf16x8 afr[4], bfr[4];
#pragma unroll
      for (int mi = 0; mi < 4; ++mi) {
        const int r = wm * 64 + mi * 16 + lr;
        afr[mi] = *(const bf16x8*)(Ab + r * 128 + (kb ^ ((r & 7) << 4)));
      }
#pragma unroll
      for (int nj = 0; nj < 4; ++nj) {
        const int r = wn * 64 + nj * 16 + lr;
        bfr[nj] = *(const bf16x8*)(Bb + r * 128 + (kb ^ ((r & 7) << 4)));
      }
#pragma unroll
      for (int mi = 0; mi < 4; ++mi)
#pragma unroll
        for (int nj = 0; nj < 4; ++nj)
          acc[mi][nj] = __builtin_amdgcn_mfma_f32_16x16x32_bf16(
              afr[mi], bfr[nj], acc[mi][nj], 0, 0, 0);
    }
    __syncthreads();                       // reads done; LDS reusable
  }

  // ---- epilogue: LDS-staged full-line streaming stores ----
  // acc[mi][nj][r] -> Y[row0 + wm*64 + mi*16 + (lane>>4)*4 + r]
  //                    [c0 + wn*64 + nj*16 + lr]
  float bvn[4];
#pragma unroll
  for (int nj = 0; nj < 4; ++nj) {
    const int c = c0 + wn * 64 + nj * 16 + lr;
    bvn[nj] = (c < C_DIM) ? bias[c] : 0.f;
  }

  char* obuf = (char*)&As[0];                    // 32KB (As+Bs), dead now
  const int cwb = (C_DIM - c0 < 128 ? C_DIM - c0 : 128) * 4; // bytes/row
  const int rwp = wid * 2;                       // wave's row pair base
  const int rsel = lane >> 5;                    // 0/1 within pair
  const int cb  = (lane & 31) * 16;              // byte col within row

#pragma unroll
  for (int slice = 0; slice < 2; ++slice) {      // 64 rows each
    __syncthreads();                             // LDS free for this slice
    if (wm == slice) {
#pragma unroll
      for (int mi = 0; mi < 4; ++mi) {
#pragma unroll
        for (int nj = 0; nj < 4; ++nj) {
          const int cl = (wn * 64 + nj * 16 + lr) * 4;
#pragma unroll
          for (int r = 0; r < 4; ++r) {
            const int rl = mi * 16 + (lane >> 4) * 4 + r;    // 0..63
            *(float*)(obuf + ((rl * 512 + cl) ^ ((rl & 7) << 4))) =
                acc[mi][nj][r] + bvn[nj];
          }
        }
      }
    }
    __syncthreads();                             // slice fully written
    // stream: 8 passes; one wave covers 2 rows x 512B (full 128B lines)
#pragma unroll
    for (int pass = 0; pass < 8; ++pass) {
      const int rl = pass * 8 + rwp + rsel;      // 0..63
      const f32x4 v =
          *(const f32x4*)(obuf + ((rl * 512 + cb) ^ ((rl & 7) << 4)));
      if (cb < cwb) {
        const int64_t m = row0 + slice * 64 + rl;
        f32x4* dst = (f32x4*)((char*)(Y + m * (int64_t)C_DIM) + c0 * 4 + cb);
        __builtin_nontemporal_store(v, dst);
      }
    }
  }
}

// ---------------------------------------------------------------------------
extern "C" void kernel_launch(void* const* d_in, const int* in_sizes, int n_in,
                              void* d_out, int out_size, void* d_ws, size_t ws_size,
                              hipStream_t stream) {
  const float* x = (const float*)d_in[0];
  const float* W = (const float*)d_in[1];
  const float* b = (const float*)d_in[2];
  float* Y = (float*)d_out;

  unsigned short* S  = (unsigned short*)d_ws;            // 50176*512 bf16 = 51.4 MB
  unsigned short* Wb = S + (size_t)M_ROWS * K_DIM;       // 1024*512 bf16  =  1.0 MB

  hipLaunchKernelGGL(lifw_kernel, dim3(LIF_BLOCKS + WCV_BLOCKS), dim3(256), 0,
                     stream, x, S, W, Wb);
  hipLaunchKernelGGL(gemm_kernel, dim3(3136), dim3(256), 0, stream, S, Wb, b, Y);
}